// Round 4
// baseline (431.293 us; speedup 1.0000x reference)
//
#include <hip/hip_runtime.h>
#include <hip/hip_bf16.h>

#define B_  2
#define S_  2048
#define D_  2048
#define H_  16
#define DK_ 128
#define M_  (B_*S_)   // 4096

typedef unsigned short u16;
typedef short bf16x8 __attribute__((ext_vector_type(8)));
typedef float f32x4  __attribute__((ext_vector_type(4)));

#define NEG_BIG (-1.0e30f)

// round-to-nearest-even fp32 -> bf16 (finite inputs)
__device__ __forceinline__ u16 f2bf(float f){
    unsigned int u = __float_as_uint(f);
    unsigned int r = (u + 0x7fffu + ((u >> 16) & 1u)) >> 16;
    return (u16)r;
}

// load 8 consecutive f32, convert to 8 bf16 packed in a uint4
__device__ __forceinline__ uint4 cvt8(const float* p){
    float4 a = *(const float4*)p;
    float4 b = *(const float4*)(p + 4);
    uint4 r;
    r.x = ((unsigned int)f2bf(a.y) << 16) | (unsigned int)f2bf(a.x);
    r.y = ((unsigned int)f2bf(a.w) << 16) | (unsigned int)f2bf(a.z);
    r.z = ((unsigned int)f2bf(b.y) << 16) | (unsigned int)f2bf(b.x);
    r.w = ((unsigned int)f2bf(b.w) << 16) | (unsigned int)f2bf(b.z);
    return r;
}

// unpack 8 bf16 (uint4) -> 8 f32
__device__ __forceinline__ void unpack8(const uint4 v, float* f){
    f[0]=__uint_as_float(v.x<<16); f[1]=__uint_as_float(v.x&0xffff0000u);
    f[2]=__uint_as_float(v.y<<16); f[3]=__uint_as_float(v.y&0xffff0000u);
    f[4]=__uint_as_float(v.z<<16); f[5]=__uint_as_float(v.z&0xffff0000u);
    f[6]=__uint_as_float(v.w<<16); f[7]=__uint_as_float(v.w&0xffff0000u);
}

// async 16B global -> LDS (gfx950). LDS dest must be wave-uniform base + lane*16.
__device__ __forceinline__ void async16(const void* g, void* l){
    __builtin_amdgcn_global_load_lds(
        (const __attribute__((address_space(1))) void*)g,
        (__attribute__((address_space(3))) void*)l, 16, 0, 0);
}

// ---------------- one-shot f32 -> bf16 conversion of all inputs ----------------
__global__ __launch_bounds__(256) void cvt_all(
    const float* __restrict__ x,  const float* __restrict__ wq, const float* __restrict__ wk,
    const float* __restrict__ wv, const float* __restrict__ wo,
    u16* __restrict__ xb, u16* __restrict__ wqb, u16* __restrict__ wkb,
    u16* __restrict__ wvb, u16* __restrict__ wob)
{
    int c = blockIdx.x*256 + threadIdx.x;
    const float* src; u16* dst; int lc;
    if      (c < 1048576){ src = x;  dst = xb;  lc = c; }
    else if (c < 1572864){ src = wq; dst = wqb; lc = c - 1048576; }
    else if (c < 2097152){ src = wk; dst = wkb; lc = c - 1572864; }
    else if (c < 2621440){ src = wv; dst = wvb; lc = c - 2097152; }
    else                 { src = wo; dst = wob; lc = c - 2621440; }
    *(uint4*)&dst[(size_t)lc*8] = cvt8(&src[(size_t)lc*8]);
}

// ---------------- 256^2-tile deep-pipelined bf16 GEMM (round 8, validated) ----------------
// BK=32, 4-slot LDS ring (128 KiB), 3-tiles-ahead prefetch via global_load_lds,
// counted s_waitcnt vmcnt(8) (never 0 in steady state), raw s_barrier (1/tile),
// setprio around MFMA clusters. 8 waves (2M x 4N), per-wave 128x64 output.
template<int MODE>
__global__ __launch_bounds__(512, 2) void gemm256(
    const u16* __restrict__ A, const u16* __restrict__ W0, const u16* __restrict__ W1,
    void* __restrict__ C0, void* __restrict__ C1)
{
    __shared__ __align__(16) u16 ring[4][2][8192];   // [slot][A|B][256 rows * 32 cols]

    const int tid  = threadIdx.x;
    const int lane = tid & 63;
    const int w    = tid >> 6;
    const int quad = lane >> 4;
    const int l15  = lane & 15;
    const int wM   = w & 1;          // M half (128 rows)
    const int wN   = w >> 1;         // N quarter (64 cols)
    const int blockN = blockIdx.x * 256;
    const int blockM = blockIdx.y * 256;

    const u16* Wm; void* Cm;
    if (MODE == 0){ Wm = blockIdx.z ? W1 : W0; Cm = blockIdx.z ? (void*)C1 : (void*)C0; }
    else          { Wm = W0; Cm = C0; }

    const int cswz = quad ^ ((l15 >> 1) & 3);   // read-side 16B-chunk swizzle

    f32x4 acc[32];
    #pragma unroll
    for (int i = 0; i < 32; ++i) acc[i] = (f32x4){0.f,0.f,0.f,0.f};

    // stage tile t (rows blockM..+256 x cols t*32..+32 of A, same for W) into ring[t&3]
    auto stage = [&](int t){
        const int k0 = t * 32;
        u16* la = (u16*)&ring[t & 3][0][0];
        u16* lb = (u16*)&ring[t & 3][1][0];
        #pragma unroll
        for (int it = 0; it < 2; ++it){
            int cc  = it*512 + tid;          // 16B chunk id, 1024 per operand tile
            int row = cc >> 2;               // 0..255
            int g   = (cc & 3) ^ ((cc >> 3) & 3);   // inverse swizzle on source
            int kb  = k0 + g*8;
            const u16* ga;
            if (MODE == 1){
                int rg = blockM + row;
                int b = rg >> 11, s2 = rg & 2047;
                int h = kb >> 7,  kk = kb & 127;
                ga = &A[(((size_t)(b*H_ + h))*S_ + s2)*DK_ + kk];
            } else {
                ga = &A[(size_t)(blockM + row)*2048 + kb];
            }
            async16(ga, la + cc*8);
            async16(&Wm[(size_t)(blockN + row)*2048 + kb], lb + cc*8);
        }
    };

    // prologue: tiles 0..2 in flight; wait tile 0 (leave 8 loads = tiles 1,2 in flight)
    stage(0); stage(1); stage(2);
    asm volatile("s_waitcnt vmcnt(8)" ::: "memory");
    __builtin_amdgcn_s_barrier();
    __builtin_amdgcn_sched_barrier(0);

    for (int t = 0; t < 64; ++t){
        const u16* la = (const u16*)&ring[t & 3][0][0];
        const u16* lb = (const u16*)&ring[t & 3][1][0];

        if (t <= 60) stage(t + 3);       // into slot (t+3)&3 = (t-1)&3: reads done

        bf16x8 bfv[4], af[4];
        #pragma unroll
        for (int ni = 0; ni < 4; ++ni)
            bfv[ni] = *(const bf16x8*)&lb[(wN*64 + ni*16 + l15)*32 + cswz*8];
        #pragma unroll
        for (int mi = 0; mi < 4; ++mi)
            af[mi]  = *(const bf16x8*)&la[(wM*128 + mi*16 + l15)*32 + cswz*8];

        __builtin_amdgcn_s_setprio(1);
        #pragma unroll
        for (int mi = 0; mi < 4; ++mi)
            #pragma unroll
            for (int ni = 0; ni < 4; ++ni)
                acc[mi*4+ni] = __builtin_amdgcn_mfma_f32_16x16x32_bf16(
                                   af[mi], bfv[ni], acc[mi*4+ni], 0, 0, 0);
        __builtin_amdgcn_s_setprio(0);

        #pragma unroll
        for (int mi = 0; mi < 4; ++mi)
            af[mi]  = *(const bf16x8*)&la[(wM*128 + 64 + mi*16 + l15)*32 + cswz*8];

        __builtin_amdgcn_s_setprio(1);
        #pragma unroll
        for (int mi = 0; mi < 4; ++mi)
            #pragma unroll
            for (int ni = 0; ni < 4; ++ni)
                acc[16 + mi*4+ni] = __builtin_amdgcn_mfma_f32_16x16x32_bf16(
                                   af[mi], bfv[ni], acc[16 + mi*4+ni], 0, 0, 0);
        __builtin_amdgcn_s_setprio(0);

        // counted waits: ensure tile t+1 resident; keep t+2/t+3 loads in flight
        if (t <= 60)      { asm volatile("s_waitcnt vmcnt(8)" ::: "memory"); }
        else if (t == 61) { asm volatile("s_waitcnt vmcnt(4)" ::: "memory"); }
        else if (t == 62) { asm volatile("s_waitcnt vmcnt(0)" ::: "memory"); }
        __builtin_amdgcn_s_barrier();
        __builtin_amdgcn_sched_barrier(0);
    }

    #pragma unroll
    for (int hf = 0; hf < 2; ++hf){
        #pragma unroll
        for (int mi = 0; mi < 4; ++mi){
            #pragma unroll
            for (int ni = 0; ni < 4; ++ni){
                #pragma unroll
                for (int r = 0; r < 4; ++r){
                    float v = acc[hf*16 + mi*4+ni][r];
                    int row = blockM + wM*128 + hf*64 + mi*16 + quad*4 + r;
                    int col = blockN + wN*64 + ni*16 + l15;
                    if (MODE == 0){
                        int b = row >> 11, s2 = row & 2047;
                        int h = col >> 7,  kk = col & 127;
                        ((u16*)Cm)[(((size_t)(b*H_ + h))*S_ + s2)*DK_ + kk] = f2bf(v);
                    } else if (MODE == 2){
                        int h = row >> 7,  kk = row & 127;
                        int b = col >> 11, s2 = col & 2047;
                        ((u16*)Cm)[(((size_t)(b*H_ + h))*DK_ + kk)*S_ + s2] = f2bf(v);
                    } else {
                        ((float*)Cm)[(size_t)row*2048 + col] = v;
                    }
                }
            }
        }
    }
}

// ---------------- fallback mixed GEMM (round-4, validated) ----------------
template<int MODE>
__global__ __launch_bounds__(256) void gemm_bt(
    const void* __restrict__ Av,
    const float* __restrict__ W0, const float* __restrict__ W1,
    void* __restrict__ C0, void* __restrict__ C1)
{
    __shared__ u16 As[128*40];
    __shared__ u16 Bs[128*40];

    const int tid  = threadIdx.x;
    const int lane = tid & 63;
    const int w    = tid >> 6;
    const int quad = lane >> 4;
    const int l15  = lane & 15;
    const int blockN = blockIdx.x * 128;
    const int blockM = blockIdx.y * 128;

    const float* Wm; void* Cm;
    if (MODE == 0){ Wm = blockIdx.z ? W1 : W0; Cm = blockIdx.z ? (void*)C1 : (void*)C0; }
    else          { Wm = W0; Cm = C0; }

    const int waveM = (w & 1) * 64;
    const int waveN = (w >> 1) * 64;

    f32x4 acc[16];
    #pragma unroll
    for (int i = 0; i < 16; ++i) acc[i] = (f32x4){0.f,0.f,0.f,0.f};

    for (int k0 = 0; k0 < 2048; k0 += 32){
        __syncthreads();
        #pragma unroll
        for (int it = 0; it < 2; ++it){
            int cc  = tid + it*256;
            int row = cc >> 2;
            int ch  = cc & 3;
            int kb  = k0 + ch*8;
            uint4 va;
            if (MODE == 1){
                int g = blockM + row;
                int b = g >> 11, s2 = g & 2047;
                int h = kb >> 7, kk = kb & 127;
                va = *(const uint4*)&((const u16*)Av)[(((size_t)(b*H_ + h))*S_ + s2)*DK_ + kk];
            } else {
                va = cvt8(&((const float*)Av)[(size_t)(blockM+row)*2048 + kb]);
            }
            uint4 vb = cvt8(&Wm[(size_t)(blockN+row)*2048 + kb]);
            *(uint4*)&As[row*40 + ch*8] = va;
            *(uint4*)&Bs[row*40 + ch*8] = vb;
        }
        __syncthreads();

        bf16x8 af[4], bfv[4];
        #pragma unroll
        for (int mi = 0; mi < 4; ++mi)
            af[mi]  = *(const bf16x8*)&As[(waveM + mi*16 + l15)*40 + quad*8];
        #pragma unroll
        for (int ni = 0; ni < 4; ++ni)
            bfv[ni] = *(const bf16x8*)&Bs[(waveN + ni*16 + l15)*40 + quad*8];
        #pragma unroll
        for (int mi = 0; mi < 4; ++mi)
            #pragma unroll
            for (int ni = 0; ni < 4; ++ni)
                acc[mi*4+ni] = __builtin_amdgcn_mfma_f32_16x16x32_bf16(
                                   af[mi], bfv[ni], acc[mi*4+ni], 0, 0, 0);
    }

    #pragma unroll
    for (int mi = 0; mi < 4; ++mi){
        #pragma unroll
        for (int ni = 0; ni < 4; ++ni){
            #pragma unroll
            for (int r = 0; r < 4; ++r){
                float v = acc[mi*4+ni][r];
                int row = blockM + waveM + mi*16 + quad*4 + r;
                int col = blockN + waveN + ni*16 + l15;
                if (MODE == 0){
                    int b = row >> 11, s2 = row & 2047;
                    int h = col >> 7,  kk = col & 127;
                    ((u16*)Cm)[(((size_t)(b*H_ + h))*S_ + s2)*DK_ + kk] = f2bf(v);
                } else if (MODE == 2){
                    int h = row >> 7,  kk = row & 127;
                    int b = col >> 11, s2 = col & 2047;
                    ((u16*)Cm)[(((size_t)(b*H_ + h))*DK_ + kk)*S_ + s2] = f2bf(v);
                } else {
                    ((float*)Cm)[(size_t)row*2048 + col] = v;
                }
            }
        }
    }
}

// In-place interleaved-pair RoPE. Q (blockIdx.y=0) is pre-scaled by log2(e)/sqrt(dk)
// so attention softmax can use exp2 directly.
__global__ __launch_bounds__(256) void rope_kernel(u16* __restrict__ Q, u16* __restrict__ K)
{
    u16* T = blockIdx.y ? K : Q;
    const float osc = blockIdx.y ? 1.0f : 0.12751743f;  // log2(e)/sqrt(128)
    int t  = blockIdx.x * 256 + threadIdx.x;
    int i0 = (t & 15) * 4;
    int s  = (t >> 4) & 2047;
    size_t base = ((size_t)(t >> 4)) * 128 + (size_t)i0 * 2;
    uint4 v = *(const uint4*)&T[base];
    float f[8]; unpack8(v, f);
    const float nl2t = -13.287712379549449f / 64.0f;  // -log2(10000)/64
    float sf = (float)s;
    unsigned int out[4];
    #pragma unroll
    for (int p = 0; p < 4; ++p){
        float inv = exp2f((float)(i0 + p) * nl2t);
        float ang = sf * inv;
        float sn, cn;
        sincosf(ang, &sn, &cn);
        float e0 = f[2*p], e1 = f[2*p+1];
        float r0 = (e0*cn - e1*sn) * osc;
        float r1 = (e1*cn + e0*sn) * osc;
        out[p] = ((unsigned int)f2bf(r1) << 16) | (unsigned int)f2bf(r0);
    }
    uint4 ov; ov.x = out[0]; ov.y = out[1]; ov.z = out[2]; ov.w = out[3];
    *(uint4*)&T[base] = ov;
}

// MFMA flash attention (round 10): 4 waves x 32 q-rows (mt=2) per 128-row block.
// Rounds 2-3 showed runtime invariant to block granularity at fixed per-q LDS
// traffic -> LDS-port-bound. K-frags (ak) and V-frags (bv) are wave-independent;
// doubling q/wave amortizes them over 2x MFMA, halving per-q LDS reads + staging.
// Keeps: async16+XOR-swizzle staging, defer-max, cvt_pk P-pack, setprio.
__global__ __launch_bounds__(256, 3) void attn_mfma(
    const u16* Q, const u16* __restrict__ K,
    const u16* __restrict__ VT, u16* O)
{
    __shared__ __align__(16) u16 Ks[64*128];     // K tile  [j][dk], chunk-swizzled
    __shared__ __align__(16) u16 Vs[128*64];     // VT tile [v][j], chunk-swizzled
    __shared__ __align__(16) u16 Ps[4][32*64];   // per-wave P [q][j], chunk-swizzled

    const int tid  = threadIdx.x;
    const int bh   = blockIdx.x;
    const int qb   = (int)gridDim.y - 1 - (int)blockIdx.y;   // heavy blocks first
    const int w    = tid >> 6;
    const int lane = tid & 63;
    const int quad = lane >> 4;
    const int l15  = lane & 15;
    const int sw   = l15 & 7;          // read-side XOR swizzle key
    const size_t qkb = (size_t)bh * S_ * DK_;

    const int qw = qb*128 + w*32;               // wave's first q row

    // Q B-frags (n = l15 = q, k = quad*8+idx), read once from global
    bf16x8 aq[2][4];
    #pragma unroll
    for (int mt = 0; mt < 2; ++mt){
        const u16* qp = &Q[qkb + (size_t)(qw + mt*16 + l15)*128 + quad*8];
        #pragma unroll
        for (int kt = 0; kt < 4; ++kt)
            aq[mt][kt] = *(const bf16x8*)(qp + kt*32);
    }

    f32x4 oa[2][8];                 // O: row q = quad*4+reg (per mt), col v = vt*16+l15
    float m_i[2], l_i[2];
    #pragma unroll
    for (int mt = 0; mt < 2; ++mt){
        #pragma unroll
        for (int vt = 0; vt < 8; ++vt) oa[mt][vt] = (f32x4){0.f,0.f,0.f,0.f};
        m_i[mt] = NEG_BIG; l_i[mt] = 0.f;
    }

    const int nkb = 2*qb + 2;
    for (int kb = 0; kb < nkb; ++kb){
        __syncthreads();
        #pragma unroll
        for (int it = 0; it < 4; ++it){              // K: 64 rows x 128, 16B chunks
            int cc  = tid + it*256;
            int row = cc >> 4, cl = cc & 15;
            async16(&K[qkb + (size_t)(kb*64 + row)*128 + (size_t)((cl ^ (row & 7))*8)],
                    &Ks[cc*8]);
        }
        #pragma unroll
        for (int it = 0; it < 4; ++it){              // VT: 128 rows x 64, 16B chunks
            int cc  = tid + it*256;
            int row = cc >> 3, cl = cc & 7;
            async16(&VT[qkb + (size_t)row*S_ + (size_t)(kb*64 + (cl ^ (row & 7))*8)],
                    &Vs[cc*8]);
        }
        __syncthreads();

        if (kb*64 > qw + 31) continue;   // wave-uniform; barriers already passed

        // S^T tile: s[mt][nt]: j = nt*16+quad*4+reg, q = mt*16+l15
        f32x4 s[2][4];
        __builtin_amdgcn_s_setprio(1);
        #pragma unroll
        for (int nt = 0; nt < 4; ++nt){
            bf16x8 ak[4];                // A-frag: m = j = nt*16+l15, k = quad*8+idx
            #pragma unroll
            for (int kt = 0; kt < 4; ++kt)
                ak[kt] = *(const bf16x8*)&Ks[(nt*16 + l15)*128 + ((kt*4 + quad) ^ sw)*8];
            #pragma unroll
            for (int mt = 0; mt < 2; ++mt){
                f32x4 a = (f32x4){0.f,0.f,0.f,0.f};
                #pragma unroll
                for (int kt = 0; kt < 4; ++kt)
                    a = __builtin_amdgcn_mfma_f32_16x16x32_bf16(ak[kt], aq[mt][kt], a, 0,0,0);
                s[mt][nt] = a;
            }
        }
        __builtin_amdgcn_s_setprio(0);

        // causal mask (diagonal tiles only): j > q -> NEG_BIG
        if (kb*64 + 63 > qw){
            #pragma unroll
            for (int mt = 0; mt < 2; ++mt){
                int qg = qw + mt*16 + l15;
                #pragma unroll
                for (int nt = 0; nt < 4; ++nt)
                    #pragma unroll
                    for (int rr = 0; rr < 4; ++rr){
                        int jg = kb*64 + nt*16 + quad*4 + rr;
                        if (jg > qg) s[mt][nt][rr] = NEG_BIG;
                    }
            }
        }

        // online softmax (exp2 domain), defer-max per mt
        #pragma unroll
        for (int mt = 0; mt < 2; ++mt){
            float mx = s[mt][0][0];
            #pragma unroll
            for (int nt = 0; nt < 4; ++nt)
                #pragma unroll
                for (int rr = 0; rr < 4; ++rr) mx = fmaxf(mx, s[mt][nt][rr]);
            mx = fmaxf(mx, __shfl_xor(mx, 16, 64));
            mx = fmaxf(mx, __shfl_xor(mx, 32, 64));

            if (!__all((mx - m_i[mt]) <= 8.0f)){
                float mn = fmaxf(m_i[mt], mx);
                float al = exp2f(m_i[mt] - mn);
                m_i[mt] = mn;
                l_i[mt] *= al;
                // alpha lives in lane with l15 == q_local; oa rows are quad*4+rr
                float al4[4];
                #pragma unroll
                for (int rr = 0; rr < 4; ++rr)
                    al4[rr] = __shfl(al, (lane & 48) | (quad*4 + rr), 64);
                #pragma unroll
                for (int vt = 0; vt < 8; ++vt)
                    #pragma unroll
                    for (int rr = 0; rr < 4; ++rr) oa[mt][vt][rr] *= al4[rr];
            }

            float ps = 0.f;
            #pragma unroll
            for (int nt = 0; nt < 4; ++nt)
                #pragma unroll
                for (int rr = 0; rr < 4; ++rr){
                    float p = exp2f(s[mt][nt][rr] - m_i[mt]);
                    s[mt][nt][rr] = p; ps += p;
                }
            ps += __shfl_xor(ps, 16, 64);
            ps += __shfl_xor(ps, 32, 64);
            l_i[mt] += ps;
        }

        // P store: pack 4 contiguous-j bf16 via v_cvt_pk_bf16_f32, swizzled chunks
        u16* pw = Ps[w];
        #pragma unroll
        for (int mt = 0; mt < 2; ++mt)
          #pragma unroll
          for (int nt = 0; nt < 4; ++nt){
              uint2 pk;
              asm("v_cvt_pk_bf16_f32 %0, %1, %2" : "=v"(pk.x) : "v"(s[mt][nt][0]), "v"(s[mt][nt][1]));
              asm("v_cvt_pk_bf16_f32 %0, %1, %2" : "=v"(pk.y) : "v"(s[mt][nt][2]), "v"(s[mt][nt][3]));
              int c = (nt*2 + (quad >> 1)) ^ sw;
              *(uint2*)&pw[(mt*16 + l15)*64 + c*8 + (quad & 1)*4] = pk;
          }

        // PV: A = P[q][j], B = VT[v][j]; bv shared across mt (the amortization)
        bf16x8 pa[2][2];
        #pragma unroll
        for (int mt = 0; mt < 2; ++mt)
          #pragma unroll
          for (int kt = 0; kt < 2; ++kt)
            pa[mt][kt] = *(const bf16x8*)&pw[(mt*16 + l15)*64 + ((kt*4 + quad) ^ sw)*8];

        __builtin_amdgcn_s_setprio(1);
        #pragma unroll
        for (int vt = 0; vt < 8; ++vt){
            bf16x8 bv[2];
            #pragma unroll
            for (int kt = 0; kt < 2; ++kt)
                bv[kt] = *(const bf16x8*)&Vs[(vt*16 + l15)*64 + ((kt*4 + quad) ^ sw)*8];
            #pragma unroll
            for (int mt = 0; mt < 2; ++mt)
              #pragma unroll
              for (int kt = 0; kt < 2; ++kt)
                oa[mt][vt] = __builtin_amdgcn_mfma_f32_16x16x32_bf16(
                                 pa[mt][kt], bv[kt], oa[mt][vt], 0,0,0);
        }
        __builtin_amdgcn_s_setprio(0);
    }

    // epilogue: normalize (1/l shuffled into oa layout, same pattern as alpha), write O
    #pragma unroll
    for (int mt = 0; mt < 2; ++mt){
        #pragma unroll
        for (int rr = 0; rr < 4; ++rr){
            float lv = __shfl(l_i[mt], (lane & 48) | (quad*4 + rr), 64);
            float inv = 1.f / lv;
            int qg = qw + mt*16 + quad*4 + rr;
            #pragma unroll
            for (int vt = 0; vt < 8; ++vt)
                O[qkb + (size_t)qg*128 + vt*16 + l15] = f2bf(oa[mt][vt][rr] * inv);
        }
    }
}

extern "C" void kernel_launch(void* const* d_in, const int* in_sizes, int n_in,
                              void* d_out, int out_size, void* d_ws, size_t ws_size,
                              hipStream_t stream)
{
    const float* x  = (const float*)d_in[0];
    const float* wq = (const float*)d_in[1];
    const float* wk = (const float*)d_in[2];
    const float* wv = (const float*)d_in[3];
    const float* wo = (const float*)d_in[4];
    float* out = (float*)d_out;

    const size_t NT = (size_t)B_ * H_ * S_ * DK_;   // 8388608 elems (16 MiB bf16)
    const size_t NW = (size_t)D_ * D_;              // 4194304 elems (8 MiB bf16)

    if (ws_size >= (size_t)50331648){
        u16* Qw  = (u16*)d_ws;
        u16* Kw  = Qw + NT;
        u16* wvb = Qw + 2*NT;
        u16* wob = wvb + NW;
        u16* xb  = (u16*)d_out;
        u16* wqb = xb + NT;
        u16* wkb = wqb + NW;
        u16* VT  = xb + NT;
        u16* Ow  = Qw;

        cvt_all<<<dim3(12288), 256, 0, stream>>>(x, wq, wk, wv, wo,
                                                 xb, wqb, wkb, wvb, wob);
        gemm256<0><<<dim3(8, 16, 2), 512, 0, stream>>>(xb, wqb, wkb, Qw, Kw);
        gemm256<2><<<dim3(16, 8, 1), 512, 0, stream>>>(wvb, xb, nullptr, VT, nullptr);
        rope_kernel<<<dim3(4096, 2), 256, 0, stream>>>(Qw, Kw);
        attn_mfma<<<dim3(32, 16), 256, 0, stream>>>(Qw, Kw, VT, Ow);
        gemm256<1><<<dim3(8, 16, 1), 512, 0, stream>>>(Ow, wob, nullptr, out, nullptr);
    } else {
        u16* Qw  = (u16*)d_ws;
        u16* Vtd = (u16*)d_out;
        u16* Kw  = (u16*)d_out + NT;
        u16* Ow  = Qw;
        gemm_bt<0><<<dim3(16, 32, 2), 256, 0, stream>>>(x, wq, wk, Qw, Kw);
        gemm_bt<2><<<dim3(32, 16, 1), 256, 0, stream>>>(wv, x, nullptr, Vtd, nullptr);
        rope_kernel<<<dim3(4096, 2), 256, 0, stream>>>(Qw, Kw);
        attn_mfma<<<dim3(32, 16), 256, 0, stream>>>(Qw, Kw, Vtd, Ow);
        gemm_bt<1><<<dim3(16, 32, 1), 256, 0, stream>>>(Ow, wo, nullptr, out, nullptr);
    }
}

// Round 5
// 399.616 us; speedup vs baseline: 1.0793x; 1.0793x over previous
//
#include <hip/hip_runtime.h>
#include <hip/hip_bf16.h>

#define B_  2
#define S_  2048
#define D_  2048
#define H_  16
#define DK_ 128
#define M_  (B_*S_)   // 4096

typedef unsigned short u16;
typedef short bf16x8 __attribute__((ext_vector_type(8)));
typedef float f32x4  __attribute__((ext_vector_type(4)));

#define NEG_BIG (-1.0e30f)

// round-to-nearest-even fp32 -> bf16 (finite inputs)
__device__ __forceinline__ u16 f2bf(float f){
    unsigned int u = __float_as_uint(f);
    unsigned int r = (u + 0x7fffu + ((u >> 16) & 1u)) >> 16;
    return (u16)r;
}

// load 8 consecutive f32, convert to 8 bf16 packed in a uint4
__device__ __forceinline__ uint4 cvt8(const float* p){
    float4 a = *(const float4*)p;
    float4 b = *(const float4*)(p + 4);
    uint4 r;
    r.x = ((unsigned int)f2bf(a.y) << 16) | (unsigned int)f2bf(a.x);
    r.y = ((unsigned int)f2bf(a.w) << 16) | (unsigned int)f2bf(a.z);
    r.z = ((unsigned int)f2bf(b.y) << 16) | (unsigned int)f2bf(b.x);
    r.w = ((unsigned int)f2bf(b.w) << 16) | (unsigned int)f2bf(b.z);
    return r;
}

// unpack 8 bf16 (uint4) -> 8 f32
__device__ __forceinline__ void unpack8(const uint4 v, float* f){
    f[0]=__uint_as_float(v.x<<16); f[1]=__uint_as_float(v.x&0xffff0000u);
    f[2]=__uint_as_float(v.y<<16); f[3]=__uint_as_float(v.y&0xffff0000u);
    f[4]=__uint_as_float(v.z<<16); f[5]=__uint_as_float(v.z&0xffff0000u);
    f[6]=__uint_as_float(v.w<<16); f[7]=__uint_as_float(v.w&0xffff0000u);
}

// async 16B global -> LDS (gfx950). LDS dest must be wave-uniform base + lane*16.
__device__ __forceinline__ void async16(const void* g, void* l){
    __builtin_amdgcn_global_load_lds(
        (const __attribute__((address_space(1))) void*)g,
        (__attribute__((address_space(3))) void*)l, 16, 0, 0);
}

// ---------------- one-shot f32 -> bf16 conversion of all inputs ----------------
__global__ __launch_bounds__(256) void cvt_all(
    const float* __restrict__ x,  const float* __restrict__ wq, const float* __restrict__ wk,
    const float* __restrict__ wv, const float* __restrict__ wo,
    u16* __restrict__ xb, u16* __restrict__ wqb, u16* __restrict__ wkb,
    u16* __restrict__ wvb, u16* __restrict__ wob)
{
    int c = blockIdx.x*256 + threadIdx.x;
    const float* src; u16* dst; int lc;
    if      (c < 1048576){ src = x;  dst = xb;  lc = c; }
    else if (c < 1572864){ src = wq; dst = wqb; lc = c - 1048576; }
    else if (c < 2097152){ src = wk; dst = wkb; lc = c - 1572864; }
    else if (c < 2621440){ src = wv; dst = wvb; lc = c - 2097152; }
    else                 { src = wo; dst = wob; lc = c - 2621440; }
    *(uint4*)&dst[(size_t)lc*8] = cvt8(&src[(size_t)lc*8]);
}

// ---------------- 256^2-tile deep-pipelined bf16 GEMM (round 8, validated) ----------------
// BK=32, 4-slot LDS ring (128 KiB), 3-tiles-ahead prefetch via global_load_lds,
// counted s_waitcnt vmcnt(8) (never 0 in steady state), raw s_barrier (1/tile),
// setprio around MFMA clusters. 8 waves (2M x 4N), per-wave 128x64 output.
template<int MODE>
__global__ __launch_bounds__(512, 2) void gemm256(
    const u16* __restrict__ A, const u16* __restrict__ W0, const u16* __restrict__ W1,
    void* __restrict__ C0, void* __restrict__ C1)
{
    __shared__ __align__(16) u16 ring[4][2][8192];   // [slot][A|B][256 rows * 32 cols]

    const int tid  = threadIdx.x;
    const int lane = tid & 63;
    const int w    = tid >> 6;
    const int quad = lane >> 4;
    const int l15  = lane & 15;
    const int wM   = w & 1;          // M half (128 rows)
    const int wN   = w >> 1;         // N quarter (64 cols)
    const int blockN = blockIdx.x * 256;
    const int blockM = blockIdx.y * 256;

    const u16* Wm; void* Cm;
    if (MODE == 0){ Wm = blockIdx.z ? W1 : W0; Cm = blockIdx.z ? (void*)C1 : (void*)C0; }
    else          { Wm = W0; Cm = C0; }

    const int cswz = quad ^ ((l15 >> 1) & 3);   // read-side 16B-chunk swizzle

    f32x4 acc[32];
    #pragma unroll
    for (int i = 0; i < 32; ++i) acc[i] = (f32x4){0.f,0.f,0.f,0.f};

    // stage tile t (rows blockM..+256 x cols t*32..+32 of A, same for W) into ring[t&3]
    auto stage = [&](int t){
        const int k0 = t * 32;
        u16* la = (u16*)&ring[t & 3][0][0];
        u16* lb = (u16*)&ring[t & 3][1][0];
        #pragma unroll
        for (int it = 0; it < 2; ++it){
            int cc  = it*512 + tid;          // 16B chunk id, 1024 per operand tile
            int row = cc >> 2;               // 0..255
            int g   = (cc & 3) ^ ((cc >> 3) & 3);   // inverse swizzle on source
            int kb  = k0 + g*8;
            const u16* ga;
            if (MODE == 1){
                int rg = blockM + row;
                int b = rg >> 11, s2 = rg & 2047;
                int h = kb >> 7,  kk = kb & 127;
                ga = &A[(((size_t)(b*H_ + h))*S_ + s2)*DK_ + kk];
            } else {
                ga = &A[(size_t)(blockM + row)*2048 + kb];
            }
            async16(ga, la + cc*8);
            async16(&Wm[(size_t)(blockN + row)*2048 + kb], lb + cc*8);
        }
    };

    // prologue: tiles 0..2 in flight; wait tile 0 (leave 8 loads = tiles 1,2 in flight)
    stage(0); stage(1); stage(2);
    asm volatile("s_waitcnt vmcnt(8)" ::: "memory");
    __builtin_amdgcn_s_barrier();
    __builtin_amdgcn_sched_barrier(0);

    for (int t = 0; t < 64; ++t){
        const u16* la = (const u16*)&ring[t & 3][0][0];
        const u16* lb = (const u16*)&ring[t & 3][1][0];

        if (t <= 60) stage(t + 3);       // into slot (t+3)&3 = (t-1)&3: reads done

        bf16x8 bfv[4], af[4];
        #pragma unroll
        for (int ni = 0; ni < 4; ++ni)
            bfv[ni] = *(const bf16x8*)&lb[(wN*64 + ni*16 + l15)*32 + cswz*8];
        #pragma unroll
        for (int mi = 0; mi < 4; ++mi)
            af[mi]  = *(const bf16x8*)&la[(wM*128 + mi*16 + l15)*32 + cswz*8];

        __builtin_amdgcn_s_setprio(1);
        #pragma unroll
        for (int mi = 0; mi < 4; ++mi)
            #pragma unroll
            for (int ni = 0; ni < 4; ++ni)
                acc[mi*4+ni] = __builtin_amdgcn_mfma_f32_16x16x32_bf16(
                                   af[mi], bfv[ni], acc[mi*4+ni], 0, 0, 0);
        __builtin_amdgcn_s_setprio(0);

        #pragma unroll
        for (int mi = 0; mi < 4; ++mi)
            af[mi]  = *(const bf16x8*)&la[(wM*128 + 64 + mi*16 + l15)*32 + cswz*8];

        __builtin_amdgcn_s_setprio(1);
        #pragma unroll
        for (int mi = 0; mi < 4; ++mi)
            #pragma unroll
            for (int ni = 0; ni < 4; ++ni)
                acc[16 + mi*4+ni] = __builtin_amdgcn_mfma_f32_16x16x32_bf16(
                                   af[mi], bfv[ni], acc[16 + mi*4+ni], 0, 0, 0);
        __builtin_amdgcn_s_setprio(0);

        // counted waits: ensure tile t+1 resident; keep t+2/t+3 loads in flight
        if (t <= 60)      { asm volatile("s_waitcnt vmcnt(8)" ::: "memory"); }
        else if (t == 61) { asm volatile("s_waitcnt vmcnt(4)" ::: "memory"); }
        else if (t == 62) { asm volatile("s_waitcnt vmcnt(0)" ::: "memory"); }
        __builtin_amdgcn_s_barrier();
        __builtin_amdgcn_sched_barrier(0);
    }

    #pragma unroll
    for (int hf = 0; hf < 2; ++hf){
        #pragma unroll
        for (int mi = 0; mi < 4; ++mi){
            #pragma unroll
            for (int ni = 0; ni < 4; ++ni){
                #pragma unroll
                for (int r = 0; r < 4; ++r){
                    float v = acc[hf*16 + mi*4+ni][r];
                    int row = blockM + wM*128 + hf*64 + mi*16 + quad*4 + r;
                    int col = blockN + wN*64 + ni*16 + l15;
                    if (MODE == 0){
                        int b = row >> 11, s2 = row & 2047;
                        int h = col >> 7,  kk = col & 127;
                        ((u16*)Cm)[(((size_t)(b*H_ + h))*S_ + s2)*DK_ + kk] = f2bf(v);
                    } else if (MODE == 2){
                        int h = row >> 7,  kk = row & 127;
                        int b = col >> 11, s2 = col & 2047;
                        ((u16*)Cm)[(((size_t)(b*H_ + h))*DK_ + kk)*S_ + s2] = f2bf(v);
                    } else {
                        ((float*)Cm)[(size_t)row*2048 + col] = v;
                    }
                }
            }
        }
    }
}

// ---------------- fallback mixed GEMM (round-4, validated) ----------------
template<int MODE>
__global__ __launch_bounds__(256) void gemm_bt(
    const void* __restrict__ Av,
    const float* __restrict__ W0, const float* __restrict__ W1,
    void* __restrict__ C0, void* __restrict__ C1)
{
    __shared__ u16 As[128*40];
    __shared__ u16 Bs[128*40];

    const int tid  = threadIdx.x;
    const int lane = tid & 63;
    const int w    = tid >> 6;
    const int quad = lane >> 4;
    const int l15  = lane & 15;
    const int blockN = blockIdx.x * 128;
    const int blockM = blockIdx.y * 128;

    const float* Wm; void* Cm;
    if (MODE == 0){ Wm = blockIdx.z ? W1 : W0; Cm = blockIdx.z ? (void*)C1 : (void*)C0; }
    else          { Wm = W0; Cm = C0; }

    const int waveM = (w & 1) * 64;
    const int waveN = (w >> 1) * 64;

    f32x4 acc[16];
    #pragma unroll
    for (int i = 0; i < 16; ++i) acc[i] = (f32x4){0.f,0.f,0.f,0.f};

    for (int k0 = 0; k0 < 2048; k0 += 32){
        __syncthreads();
        #pragma unroll
        for (int it = 0; it < 2; ++it){
            int cc  = tid + it*256;
            int row = cc >> 2;
            int ch  = cc & 3;
            int kb  = k0 + ch*8;
            uint4 va;
            if (MODE == 1){
                int g = blockM + row;
                int b = g >> 11, s2 = g & 2047;
                int h = kb >> 7, kk = kb & 127;
                va = *(const uint4*)&((const u16*)Av)[(((size_t)(b*H_ + h))*S_ + s2)*DK_ + kk];
            } else {
                va = cvt8(&((const float*)Av)[(size_t)(blockM+row)*2048 + kb]);
            }
            uint4 vb = cvt8(&Wm[(size_t)(blockN+row)*2048 + kb]);
            *(uint4*)&As[row*40 + ch*8] = va;
            *(uint4*)&Bs[row*40 + ch*8] = vb;
        }
        __syncthreads();

        bf16x8 af[4], bfv[4];
        #pragma unroll
        for (int mi = 0; mi < 4; ++mi)
            af[mi]  = *(const bf16x8*)&As[(waveM + mi*16 + l15)*40 + quad*8];
        #pragma unroll
        for (int ni = 0; ni < 4; ++ni)
            bfv[ni] = *(const bf16x8*)&Bs[(waveN + ni*16 + l15)*40 + quad*8];
        #pragma unroll
        for (int mi = 0; mi < 4; ++mi)
            #pragma unroll
            for (int ni = 0; ni < 4; ++ni)
                acc[mi*4+ni] = __builtin_amdgcn_mfma_f32_16x16x32_bf16(
                                   af[mi], bfv[ni], acc[mi*4+ni], 0, 0, 0);
    }

    #pragma unroll
    for (int mi = 0; mi < 4; ++mi){
        #pragma unroll
        for (int ni = 0; ni < 4; ++ni){
            #pragma unroll
            for (int r = 0; r < 4; ++r){
                float v = acc[mi*4+ni][r];
                int row = blockM + waveM + mi*16 + quad*4 + r;
                int col = blockN + waveN + ni*16 + l15;
                if (MODE == 0){
                    int b = row >> 11, s2 = row & 2047;
                    int h = col >> 7,  kk = col & 127;
                    ((u16*)Cm)[(((size_t)(b*H_ + h))*S_ + s2)*DK_ + kk] = f2bf(v);
                } else if (MODE == 2){
                    int h = row >> 7,  kk = row & 127;
                    int b = col >> 11, s2 = col & 2047;
                    ((u16*)Cm)[(((size_t)(b*H_ + h))*DK_ + kk)*S_ + s2] = f2bf(v);
                } else {
                    ((float*)Cm)[(size_t)row*2048 + col] = v;
                }
            }
        }
    }
}

// In-place interleaved-pair RoPE. Q (blockIdx.y=0) is pre-scaled by log2(e)/sqrt(dk)
// so attention softmax can use exp2 directly.
__global__ __launch_bounds__(256) void rope_kernel(u16* __restrict__ Q, u16* __restrict__ K)
{
    u16* T = blockIdx.y ? K : Q;
    const float osc = blockIdx.y ? 1.0f : 0.12751743f;  // log2(e)/sqrt(128)
    int t  = blockIdx.x * 256 + threadIdx.x;
    int i0 = (t & 15) * 4;
    int s  = (t >> 4) & 2047;
    size_t base = ((size_t)(t >> 4)) * 128 + (size_t)i0 * 2;
    uint4 v = *(const uint4*)&T[base];
    float f[8]; unpack8(v, f);
    const float nl2t = -13.287712379549449f / 64.0f;  // -log2(10000)/64
    float sf = (float)s;
    unsigned int out[4];
    #pragma unroll
    for (int p = 0; p < 4; ++p){
        float inv = exp2f((float)(i0 + p) * nl2t);
        float ang = sf * inv;
        float sn, cn;
        sincosf(ang, &sn, &cn);
        float e0 = f[2*p], e1 = f[2*p+1];
        float r0 = (e0*cn - e1*sn) * osc;
        float r1 = (e1*cn + e0*sn) * osc;
        out[p] = ((unsigned int)f2bf(r1) << 16) | (unsigned int)f2bf(r0);
    }
    uint4 ov; ov.x = out[0]; ov.y = out[1]; ov.z = out[2]; ov.w = out[3];
    *(uint4*)&T[base] = ov;
}

// MFMA flash attention (round 11): back to the round-3 structure (4 waves x 16
// q-rows per 64-row block, 1024 blocks — best measured, 82.4 us), now with
// DOUBLE-BUFFERED K/V staging (2-phase pipeline, T3-minimum): stage tile kb+1
// into buf^1 BEFORE computing tile kb from buf, single __syncthreads per
// iteration (its implicit vmcnt(0) drain lands after compute has hidden the
// HBM/L2 latency). R4 taught: latency-chain-bound, wave count is binding; this
// removes the per-step staging drain without reducing resident waves.
// One-barrier write/read separation — same discipline as the gemm256 ring.
__global__ __launch_bounds__(256, 4) void attn_mfma(
    const u16* Q, const u16* __restrict__ K,
    const u16* __restrict__ VT, u16* O)
{
    __shared__ __align__(16) u16 Ks[2][64*128];  // K tile  [j][dk], chunk-swizzled
    __shared__ __align__(16) u16 Vs[2][128*64];  // VT tile [v][j], chunk-swizzled
    __shared__ __align__(16) u16 Ps[4][16*64];   // per-wave P [q][j], chunk-swizzled

    const int tid  = threadIdx.x;
    const int bh   = blockIdx.x;
    const int qb   = (int)gridDim.y - 1 - (int)blockIdx.y;   // heavy blocks first
    const int w    = tid >> 6;
    const int lane = tid & 63;
    const int quad = lane >> 4;
    const int l15  = lane & 15;
    const int sw   = l15 & 7;          // read-side XOR swizzle key
    const size_t qkb = (size_t)bh * S_ * DK_;

    const int qw = qb*64 + w*16;                // wave's first q row

    bf16x8 aq[4];
    {
        const u16* qp = &Q[qkb + (size_t)(qw + l15)*128 + quad*8];
        #pragma unroll
        for (int kt = 0; kt < 4; ++kt)
            aq[kt] = *(const bf16x8*)(qp + kt*32);
    }

    f32x4 oa[8];
    #pragma unroll
    for (int vt = 0; vt < 8; ++vt) oa[vt] = (f32x4){0.f,0.f,0.f,0.f};
    float m_i = NEG_BIG, l_i = 0.f;

    // stage KV tile kb into buffer buf (issue-only; no wait here)
    auto stage = [&](int kb, int buf){
        #pragma unroll
        for (int it = 0; it < 4; ++it){              // K: 64 rows x 128, 16B chunks
            int cc  = tid + it*256;
            int row = cc >> 4, cl = cc & 15;
            async16(&K[qkb + (size_t)(kb*64 + row)*128 + (size_t)((cl ^ (row & 7))*8)],
                    &Ks[buf][cc*8]);
        }
        #pragma unroll
        for (int it = 0; it < 4; ++it){              // VT: 128 rows x 64, 16B chunks
            int cc  = tid + it*256;
            int row = cc >> 3, cl = cc & 7;
            async16(&VT[qkb + (size_t)row*S_ + (size_t)(kb*64 + (cl ^ (row & 7))*8)],
                    &Vs[buf][cc*8]);
        }
    };

    const int nkb = qb + 1;
    stage(0, 0);
    __syncthreads();   // drains vmcnt(0): tile 0 resident

    for (int kb = 0; kb < nkb; ++kb){
        const int cur = kb & 1;
        if (kb + 1 < nkb) stage(kb + 1, cur ^ 1);   // prefetch next, flies under compute

        const u16* ks = &Ks[cur][0];
        const u16* vs = &Vs[cur][0];

        f32x4 s[4];
        __builtin_amdgcn_s_setprio(1);
        #pragma unroll
        for (int nt = 0; nt < 4; ++nt){
            f32x4 a = (f32x4){0.f,0.f,0.f,0.f};
            #pragma unroll
            for (int kt = 0; kt < 4; ++kt){
                bf16x8 ak = *(const bf16x8*)&ks[(nt*16 + l15)*128 + ((kt*4 + quad) ^ sw)*8];
                a = __builtin_amdgcn_mfma_f32_16x16x32_bf16(ak, aq[kt], a, 0,0,0);
            }
            s[nt] = a;
        }
        __builtin_amdgcn_s_setprio(0);

        if (kb == nkb - 1){          // diagonal tile: causal mask j > q -> NEG_BIG
            int qg = qw + l15;
            #pragma unroll
            for (int nt = 0; nt < 4; ++nt)
                #pragma unroll
                for (int rr = 0; rr < 4; ++rr){
                    int jg = kb*64 + nt*16 + quad*4 + rr;
                    if (jg > qg) s[nt][rr] = NEG_BIG;
                }
        }

        float mx = s[0][0];
        #pragma unroll
        for (int nt = 0; nt < 4; ++nt)
            #pragma unroll
            for (int rr = 0; rr < 4; ++rr) mx = fmaxf(mx, s[nt][rr]);
        mx = fmaxf(mx, __shfl_xor(mx, 16, 64));
        mx = fmaxf(mx, __shfl_xor(mx, 32, 64));

        if (!__all((mx - m_i) <= 8.0f)){
            float mn = fmaxf(m_i, mx);
            float al = exp2f(m_i - mn);
            m_i = mn;
            l_i *= al;
            float al4[4];
            #pragma unroll
            for (int rr = 0; rr < 4; ++rr)
                al4[rr] = __shfl(al, (lane & 48) | (quad*4 + rr), 64);
            #pragma unroll
            for (int vt = 0; vt < 8; ++vt)
                #pragma unroll
                for (int rr = 0; rr < 4; ++rr) oa[vt][rr] *= al4[rr];
        }

        float ps = 0.f;
        #pragma unroll
        for (int nt = 0; nt < 4; ++nt)
            #pragma unroll
            for (int rr = 0; rr < 4; ++rr){
                float p = exp2f(s[nt][rr] - m_i);
                s[nt][rr] = p; ps += p;
            }
        ps += __shfl_xor(ps, 16, 64);
        ps += __shfl_xor(ps, 32, 64);
        l_i += ps;

        u16* pw = Ps[w];
        #pragma unroll
        for (int nt = 0; nt < 4; ++nt){
            uint2 pk;
            asm("v_cvt_pk_bf16_f32 %0, %1, %2" : "=v"(pk.x) : "v"(s[nt][0]), "v"(s[nt][1]));
            asm("v_cvt_pk_bf16_f32 %0, %1, %2" : "=v"(pk.y) : "v"(s[nt][2]), "v"(s[nt][3]));
            int c = (nt*2 + (quad >> 1)) ^ sw;
            *(uint2*)&pw[l15*64 + c*8 + (quad & 1)*4] = pk;
        }

        bf16x8 pa[2];
        #pragma unroll
        for (int kt = 0; kt < 2; ++kt)
            pa[kt] = *(const bf16x8*)&pw[l15*64 + ((kt*4 + quad) ^ sw)*8];

        __builtin_amdgcn_s_setprio(1);
        #pragma unroll
        for (int vt = 0; vt < 8; ++vt){
            #pragma unroll
            for (int kt = 0; kt < 2; ++kt){
                bf16x8 bv = *(const bf16x8*)&vs[(vt*16 + l15)*64 + ((kt*4 + quad) ^ sw)*8];
                oa[vt] = __builtin_amdgcn_mfma_f32_16x16x32_bf16(pa[kt], bv, oa[vt], 0,0,0);
            }
        }
        __builtin_amdgcn_s_setprio(0);

        // end-of-iter: implicit vmcnt(0) drain (prefetch landed under compute) + publish
        __syncthreads();
    }

    #pragma unroll
    for (int rr = 0; rr < 4; ++rr){
        float lv = __shfl(l_i, (lane & 48) | (quad*4 + rr), 64);
        float inv = 1.f / lv;
        int qg = qw + quad*4 + rr;
        #pragma unroll
        for (int vt = 0; vt < 8; ++vt)
            O[qkb + (size_t)qg*128 + vt*16 + l15] = f2bf(oa[vt][rr] * inv);
    }
}

extern "C" void kernel_launch(void* const* d_in, const int* in_sizes, int n_in,
                              void* d_out, int out_size, void* d_ws, size_t ws_size,
                              hipStream_t stream)
{
    const float* x  = (const float*)d_in[0];
    const float* wq = (const float*)d_in[1];
    const float* wk = (const float*)d_in[2];
    const float* wv = (const float*)d_in[3];
    const float* wo = (const float*)d_in[4];
    float* out = (float*)d_out;

    const size_t NT = (size_t)B_ * H_ * S_ * DK_;   // 8388608 elems (16 MiB bf16)
    const size_t NW = (size_t)D_ * D_;              // 4194304 elems (8 MiB bf16)

    if (ws_size >= (size_t)50331648){
        u16* Qw  = (u16*)d_ws;
        u16* Kw  = Qw + NT;
        u16* wvb = Qw + 2*NT;
        u16* wob = wvb + NW;
        u16* xb  = (u16*)d_out;
        u16* wqb = xb + NT;
        u16* wkb = wqb + NW;
        u16* VT  = xb + NT;
        u16* Ow  = Qw;

        cvt_all<<<dim3(12288), 256, 0, stream>>>(x, wq, wk, wv, wo,
                                                 xb, wqb, wkb, wvb, wob);
        gemm256<0><<<dim3(8, 16, 2), 512, 0, stream>>>(xb, wqb, wkb, Qw, Kw);
        gemm256<2><<<dim3(16, 8, 1), 512, 0, stream>>>(wvb, xb, nullptr, VT, nullptr);
        rope_kernel<<<dim3(4096, 2), 256, 0, stream>>>(Qw, Kw);
        attn_mfma<<<dim3(32, 32), 256, 0, stream>>>(Qw, Kw, VT, Ow);
        gemm256<1><<<dim3(8, 16, 1), 512, 0, stream>>>(Ow, wob, nullptr, out, nullptr);
    } else {
        u16* Qw  = (u16*)d_ws;
        u16* Vtd = (u16*)d_out;
        u16* Kw  = (u16*)d_out + NT;
        u16* Ow  = Qw;
        gemm_bt<0><<<dim3(16, 32, 2), 256, 0, stream>>>(x, wq, wk, Qw, Kw);
        gemm_bt<2><<<dim3(32, 16, 1), 256, 0, stream>>>(wv, x, nullptr, Vtd, nullptr);
        rope_kernel<<<dim3(4096, 2), 256, 0, stream>>>(Qw, Kw);
        attn_mfma<<<dim3(32, 32), 256, 0, stream>>>(Qw, Kw, Vtd, Ow);
        gemm_bt<1><<<dim3(16, 32, 1), 256, 0, stream>>>(Ow, wo, nullptr, out, nullptr);
    }
}

// Round 6
// 366.257 us; speedup vs baseline: 1.1776x; 1.0911x over previous
//
#include <hip/hip_runtime.h>
#include <hip/hip_bf16.h>

#define B_  2
#define S_  2048
#define D_  2048
#define H_  16
#define DK_ 128
#define M_  (B_*S_)   // 4096

typedef unsigned short u16;
typedef short bf16x8 __attribute__((ext_vector_type(8)));
typedef float f32x4  __attribute__((ext_vector_type(4)));

#define NEG_BIG (-1.0e30f)

// round-to-nearest-even fp32 -> bf16 (finite inputs)
__device__ __forceinline__ u16 f2bf(float f){
    unsigned int u = __float_as_uint(f);
    unsigned int r = (u + 0x7fffu + ((u >> 16) & 1u)) >> 16;
    return (u16)r;
}

// load 8 consecutive f32, convert to 8 bf16 packed in a uint4
__device__ __forceinline__ uint4 cvt8(const float* p){
    float4 a = *(const float4*)p;
    float4 b = *(const float4*)(p + 4);
    uint4 r;
    r.x = ((unsigned int)f2bf(a.y) << 16) | (unsigned int)f2bf(a.x);
    r.y = ((unsigned int)f2bf(a.w) << 16) | (unsigned int)f2bf(a.z);
    r.z = ((unsigned int)f2bf(b.y) << 16) | (unsigned int)f2bf(b.x);
    r.w = ((unsigned int)f2bf(b.w) << 16) | (unsigned int)f2bf(b.z);
    return r;
}

// unpack 8 bf16 (uint4) -> 8 f32
__device__ __forceinline__ void unpack8(const uint4 v, float* f){
    f[0]=__uint_as_float(v.x<<16); f[1]=__uint_as_float(v.x&0xffff0000u);
    f[2]=__uint_as_float(v.y<<16); f[3]=__uint_as_float(v.y&0xffff0000u);
    f[4]=__uint_as_float(v.z<<16); f[5]=__uint_as_float(v.z&0xffff0000u);
    f[6]=__uint_as_float(v.w<<16); f[7]=__uint_as_float(v.w&0xffff0000u);
}

// async 16B global -> LDS (gfx950). LDS dest must be wave-uniform base + lane*16.
__device__ __forceinline__ void async16(const void* g, void* l){
    __builtin_amdgcn_global_load_lds(
        (const __attribute__((address_space(1))) void*)g,
        (__attribute__((address_space(3))) void*)l, 16, 0, 0);
}

// ---------------- one-shot f32 -> bf16 conversion of all inputs ----------------
__global__ __launch_bounds__(256) void cvt_all(
    const float* __restrict__ x,  const float* __restrict__ wq, const float* __restrict__ wk,
    const float* __restrict__ wv, const float* __restrict__ wo,
    u16* __restrict__ xb, u16* __restrict__ wqb, u16* __restrict__ wkb,
    u16* __restrict__ wvb, u16* __restrict__ wob)
{
    int c = blockIdx.x*256 + threadIdx.x;
    const float* src; u16* dst; int lc;
    if      (c < 1048576){ src = x;  dst = xb;  lc = c; }
    else if (c < 1572864){ src = wq; dst = wqb; lc = c - 1048576; }
    else if (c < 2097152){ src = wk; dst = wkb; lc = c - 1572864; }
    else if (c < 2621440){ src = wv; dst = wvb; lc = c - 2097152; }
    else                 { src = wo; dst = wob; lc = c - 2621440; }
    *(uint4*)&dst[(size_t)lc*8] = cvt8(&src[(size_t)lc*8]);
}

// ---------------- 256xBN-tile deep-pipelined bf16 GEMM (round 12) ----------------
// Round-6 grid analysis: V-proj (16x8) and O-proj (8x16) dispatches were 128-block
// = HALF-GPU at 1 block/CU -> each cost ~a full QK dispatch for half the FLOPs.
// Template NF (N-frags/wave): BN = NF*64. NF=4 (BN=256) for QK (unchanged,
// validated). NF=2 (BN=128) for V/O -> 256-block full-GPU grids, half work/block.
// BK=32, 4-slot LDS ring, 3-tiles-ahead prefetch via global_load_lds, counted
// s_waitcnt vmcnt(2L/L/0), L = loads/tile/thread = 2+BN/128. Raw s_barrier 1/tile.
template<int MODE, int NF>
__global__ __launch_bounds__(512, 2) void gemm256(
    const u16* __restrict__ A, const u16* __restrict__ W0, const u16* __restrict__ W1,
    void* __restrict__ C0, void* __restrict__ C1)
{
    constexpr int BN = NF * 64;
    __shared__ __align__(16) u16 ring[4][(256 + BN) * 32];   // [slot][A rows | B rows]

    const int tid  = threadIdx.x;
    const int lane = tid & 63;
    const int w    = tid >> 6;
    const int quad = lane >> 4;
    const int l15  = lane & 15;
    const int wM   = w & 1;          // M half (128 rows)
    const int wN   = w >> 1;         // N quarter (NF*16 cols)
    const int blockN = blockIdx.x * BN;
    const int blockM = blockIdx.y * 256;

    const u16* Wm; void* Cm;
    if (MODE == 0){ Wm = blockIdx.z ? W1 : W0; Cm = blockIdx.z ? (void*)C1 : (void*)C0; }
    else          { Wm = W0; Cm = C0; }

    const int cswz = quad ^ ((l15 >> 1) & 3);   // read-side 16B-chunk swizzle

    f32x4 acc[8 * NF];
    #pragma unroll
    for (int i = 0; i < 8 * NF; ++i) acc[i] = (f32x4){0.f,0.f,0.f,0.f};

    // stage tile t (rows blockM..+256 of A, blockN..+BN of W, cols t*32..+32)
    auto stage = [&](int t){
        const int k0 = t * 32;
        u16* la = (u16*)&ring[t & 3][0];
        u16* lb = la + 256*32;
        #pragma unroll
        for (int it = 0; it < 2; ++it){            // A: 1024 chunks
            int cc  = it*512 + tid;
            int row = cc >> 2;
            int g   = (cc & 3) ^ ((cc >> 3) & 3);  // inverse swizzle on source
            int kb  = k0 + g*8;
            const u16* ga;
            if (MODE == 1){
                int rg = blockM + row;
                int b = rg >> 11, s2 = rg & 2047;
                int h = kb >> 7,  kk = kb & 127;
                ga = &A[(((size_t)(b*H_ + h))*S_ + s2)*DK_ + kk];
            } else {
                ga = &A[(size_t)(blockM + row)*2048 + kb];
            }
            async16(ga, la + cc*8);
        }
        #pragma unroll
        for (int it = 0; it < BN/128; ++it){       // B: BN*4 chunks
            int cc  = it*512 + tid;
            int row = cc >> 2;
            int g   = (cc & 3) ^ ((cc >> 3) & 3);
            int kb  = k0 + g*8;
            async16(&Wm[(size_t)(blockN + row)*2048 + kb], lb + cc*8);
        }
    };

    // prologue: tiles 0..2 in flight; ensure tile 0 resident (2 tiles stay in flight)
    stage(0); stage(1); stage(2);
    if constexpr (NF == 4) asm volatile("s_waitcnt vmcnt(8)" ::: "memory");
    else                   asm volatile("s_waitcnt vmcnt(6)" ::: "memory");
    __builtin_amdgcn_s_barrier();
    __builtin_amdgcn_sched_barrier(0);

    for (int t = 0; t < 64; ++t){
        const u16* la = (const u16*)&ring[t & 3][0];
        const u16* lb = la + 256*32;

        if (t <= 60) stage(t + 3);       // into slot (t+3)&3 = (t-1)&3: reads done

        bf16x8 bfv[NF];
        #pragma unroll
        for (int ni = 0; ni < NF; ++ni)
            bfv[ni] = *(const bf16x8*)&lb[(wN*(NF*16) + ni*16 + l15)*32 + cswz*8];

        #pragma unroll
        for (int hf = 0; hf < 2; ++hf){
            bf16x8 af[4];
            #pragma unroll
            for (int mi = 0; mi < 4; ++mi)
                af[mi] = *(const bf16x8*)&la[(wM*128 + hf*64 + mi*16 + l15)*32 + cswz*8];
            __builtin_amdgcn_s_setprio(1);
            #pragma unroll
            for (int mi = 0; mi < 4; ++mi)
                #pragma unroll
                for (int ni = 0; ni < NF; ++ni)
                    acc[(hf*4 + mi)*NF + ni] = __builtin_amdgcn_mfma_f32_16x16x32_bf16(
                        af[mi], bfv[ni], acc[(hf*4 + mi)*NF + ni], 0, 0, 0);
            __builtin_amdgcn_s_setprio(0);
        }

        // counted waits: ensure tile t+1 resident; keep t+2/t+3 loads in flight
        if constexpr (NF == 4){
            if (t <= 60)      { asm volatile("s_waitcnt vmcnt(8)" ::: "memory"); }
            else if (t == 61) { asm volatile("s_waitcnt vmcnt(4)" ::: "memory"); }
            else if (t == 62) { asm volatile("s_waitcnt vmcnt(0)" ::: "memory"); }
        } else {
            if (t <= 60)      { asm volatile("s_waitcnt vmcnt(6)" ::: "memory"); }
            else if (t == 61) { asm volatile("s_waitcnt vmcnt(3)" ::: "memory"); }
            else if (t == 62) { asm volatile("s_waitcnt vmcnt(0)" ::: "memory"); }
        }
        __builtin_amdgcn_s_barrier();
        __builtin_amdgcn_sched_barrier(0);
    }

    #pragma unroll
    for (int hf = 0; hf < 2; ++hf){
        #pragma unroll
        for (int mi = 0; mi < 4; ++mi){
            #pragma unroll
            for (int ni = 0; ni < NF; ++ni){
                #pragma unroll
                for (int r = 0; r < 4; ++r){
                    float v = acc[(hf*4 + mi)*NF + ni][r];
                    int row = blockM + wM*128 + hf*64 + mi*16 + quad*4 + r;
                    int col = blockN + wN*(NF*16) + ni*16 + l15;
                    if (MODE == 0){
                        int b = row >> 11, s2 = row & 2047;
                        int h = col >> 7,  kk = col & 127;
                        ((u16*)Cm)[(((size_t)(b*H_ + h))*S_ + s2)*DK_ + kk] = f2bf(v);
                    } else if (MODE == 2){
                        int h = row >> 7,  kk = row & 127;
                        int b = col >> 11, s2 = col & 2047;
                        ((u16*)Cm)[(((size_t)(b*H_ + h))*DK_ + kk)*S_ + s2] = f2bf(v);
                    } else {
                        ((float*)Cm)[(size_t)row*2048 + col] = v;
                    }
                }
            }
        }
    }
}

// ---------------- fallback mixed GEMM (round-4, validated) ----------------
template<int MODE>
__global__ __launch_bounds__(256) void gemm_bt(
    const void* __restrict__ Av,
    const float* __restrict__ W0, const float* __restrict__ W1,
    void* __restrict__ C0, void* __restrict__ C1)
{
    __shared__ u16 As[128*40];
    __shared__ u16 Bs[128*40];

    const int tid  = threadIdx.x;
    const int lane = tid & 63;
    const int w    = tid >> 6;
    const int quad = lane >> 4;
    const int l15  = lane & 15;
    const int blockN = blockIdx.x * 128;
    const int blockM = blockIdx.y * 128;

    const float* Wm; void* Cm;
    if (MODE == 0){ Wm = blockIdx.z ? W1 : W0; Cm = blockIdx.z ? (void*)C1 : (void*)C0; }
    else          { Wm = W0; Cm = C0; }

    const int waveM = (w & 1) * 64;
    const int waveN = (w >> 1) * 64;

    f32x4 acc[16];
    #pragma unroll
    for (int i = 0; i < 16; ++i) acc[i] = (f32x4){0.f,0.f,0.f,0.f};

    for (int k0 = 0; k0 < 2048; k0 += 32){
        __syncthreads();
        #pragma unroll
        for (int it = 0; it < 2; ++it){
            int cc  = tid + it*256;
            int row = cc >> 2;
            int ch  = cc & 3;
            int kb  = k0 + ch*8;
            uint4 va;
            if (MODE == 1){
                int g = blockM + row;
                int b = g >> 11, s2 = g & 2047;
                int h = kb >> 7, kk = kb & 127;
                va = *(const uint4*)&((const u16*)Av)[(((size_t)(b*H_ + h))*S_ + s2)*DK_ + kk];
            } else {
                va = cvt8(&((const float*)Av)[(size_t)(blockM+row)*2048 + kb]);
            }
            uint4 vb = cvt8(&Wm[(size_t)(blockN+row)*2048 + kb]);
            *(uint4*)&As[row*40 + ch*8] = va;
            *(uint4*)&Bs[row*40 + ch*8] = vb;
        }
        __syncthreads();

        bf16x8 af[4], bfv[4];
        #pragma unroll
        for (int mi = 0; mi < 4; ++mi)
            af[mi]  = *(const bf16x8*)&As[(waveM + mi*16 + l15)*40 + quad*8];
        #pragma unroll
        for (int ni = 0; ni < 4; ++ni)
            bfv[ni] = *(const bf16x8*)&Bs[(waveN + ni*16 + l15)*40 + quad*8];
        #pragma unroll
        for (int mi = 0; mi < 4; ++mi)
            #pragma unroll
            for (int ni = 0; ni < 4; ++ni)
                acc[mi*4+ni] = __builtin_amdgcn_mfma_f32_16x16x32_bf16(
                                   af[mi], bfv[ni], acc[mi*4+ni], 0, 0, 0);
    }

    #pragma unroll
    for (int mi = 0; mi < 4; ++mi){
        #pragma unroll
        for (int ni = 0; ni < 4; ++ni){
            #pragma unroll
            for (int r = 0; r < 4; ++r){
                float v = acc[mi*4+ni][r];
                int row = blockM + waveM + mi*16 + quad*4 + r;
                int col = blockN + waveN + ni*16 + l15;
                if (MODE == 0){
                    int b = row >> 11, s2 = row & 2047;
                    int h = col >> 7,  kk = col & 127;
                    ((u16*)Cm)[(((size_t)(b*H_ + h))*S_ + s2)*DK_ + kk] = f2bf(v);
                } else if (MODE == 2){
                    int h = row >> 7,  kk = row & 127;
                    int b = col >> 11, s2 = col & 2047;
                    ((u16*)Cm)[(((size_t)(b*H_ + h))*DK_ + kk)*S_ + s2] = f2bf(v);
                } else {
                    ((float*)Cm)[(size_t)row*2048 + col] = v;
                }
            }
        }
    }
}

// In-place interleaved-pair RoPE. Q (blockIdx.y=0) is pre-scaled by log2(e)/sqrt(dk)
// so attention softmax can use exp2 directly.
__global__ __launch_bounds__(256) void rope_kernel(u16* __restrict__ Q, u16* __restrict__ K)
{
    u16* T = blockIdx.y ? K : Q;
    const float osc = blockIdx.y ? 1.0f : 0.12751743f;  // log2(e)/sqrt(128)
    int t  = blockIdx.x * 256 + threadIdx.x;
    int i0 = (t & 15) * 4;
    int s  = (t >> 4) & 2047;
    size_t base = ((size_t)(t >> 4)) * 128 + (size_t)i0 * 2;
    uint4 v = *(const uint4*)&T[base];
    float f[8]; unpack8(v, f);
    const float nl2t = -13.287712379549449f / 64.0f;  // -log2(10000)/64
    float sf = (float)s;
    unsigned int out[4];
    #pragma unroll
    for (int p = 0; p < 4; ++p){
        float inv = exp2f((float)(i0 + p) * nl2t);
        float ang = sf * inv;
        float sn, cn;
        sincosf(ang, &sn, &cn);
        float e0 = f[2*p], e1 = f[2*p+1];
        float r0 = (e0*cn - e1*sn) * osc;
        float r1 = (e1*cn + e0*sn) * osc;
        out[p] = ((unsigned int)f2bf(r1) << 16) | (unsigned int)f2bf(r0);
    }
    uint4 ov; ov.x = out[0]; ov.y = out[1]; ov.z = out[2]; ov.w = out[3];
    *(uint4*)&T[base] = ov;
}

// MFMA flash attention (round-5 validated): 4 waves x 16 q-rows per 64-row block,
// double-buffered K/V staging, defer-max, cvt_pk P-pack, setprio.
__global__ __launch_bounds__(256, 4) void attn_mfma(
    const u16* Q, const u16* __restrict__ K,
    const u16* __restrict__ VT, u16* O)
{
    __shared__ __align__(16) u16 Ks[2][64*128];  // K tile  [j][dk], chunk-swizzled
    __shared__ __align__(16) u16 Vs[2][128*64];  // VT tile [v][j], chunk-swizzled
    __shared__ __align__(16) u16 Ps[4][16*64];   // per-wave P [q][j], chunk-swizzled

    const int tid  = threadIdx.x;
    const int bh   = blockIdx.x;
    const int qb   = (int)gridDim.y - 1 - (int)blockIdx.y;   // heavy blocks first
    const int w    = tid >> 6;
    const int lane = tid & 63;
    const int quad = lane >> 4;
    const int l15  = lane & 15;
    const int sw   = l15 & 7;          // read-side XOR swizzle key
    const size_t qkb = (size_t)bh * S_ * DK_;

    const int qw = qb*64 + w*16;                // wave's first q row

    bf16x8 aq[4];
    {
        const u16* qp = &Q[qkb + (size_t)(qw + l15)*128 + quad*8];
        #pragma unroll
        for (int kt = 0; kt < 4; ++kt)
            aq[kt] = *(const bf16x8*)(qp + kt*32);
    }

    f32x4 oa[8];
    #pragma unroll
    for (int vt = 0; vt < 8; ++vt) oa[vt] = (f32x4){0.f,0.f,0.f,0.f};
    float m_i = NEG_BIG, l_i = 0.f;

    // stage KV tile kb into buffer buf (issue-only; no wait here)
    auto stage = [&](int kb, int buf){
        #pragma unroll
        for (int it = 0; it < 4; ++it){              // K: 64 rows x 128, 16B chunks
            int cc  = tid + it*256;
            int row = cc >> 4, cl = cc & 15;
            async16(&K[qkb + (size_t)(kb*64 + row)*128 + (size_t)((cl ^ (row & 7))*8)],
                    &Ks[buf][cc*8]);
        }
        #pragma unroll
        for (int it = 0; it < 4; ++it){              // VT: 128 rows x 64, 16B chunks
            int cc  = tid + it*256;
            int row = cc >> 3, cl = cc & 7;
            async16(&VT[qkb + (size_t)row*S_ + (size_t)(kb*64 + (cl ^ (row & 7))*8)],
                    &Vs[buf][cc*8]);
        }
    };

    const int nkb = qb + 1;
    stage(0, 0);
    __syncthreads();   // drains vmcnt(0): tile 0 resident

    for (int kb = 0; kb < nkb; ++kb){
        const int cur = kb & 1;
        if (kb + 1 < nkb) stage(kb + 1, cur ^ 1);   // prefetch next, flies under compute

        const u16* ks = &Ks[cur][0];
        const u16* vs = &Vs[cur][0];

        f32x4 s[4];
        __builtin_amdgcn_s_setprio(1);
        #pragma unroll
        for (int nt = 0; nt < 4; ++nt){
            f32x4 a = (f32x4){0.f,0.f,0.f,0.f};
            #pragma unroll
            for (int kt = 0; kt < 4; ++kt){
                bf16x8 ak = *(const bf16x8*)&ks[(nt*16 + l15)*128 + ((kt*4 + quad) ^ sw)*8];
                a = __builtin_amdgcn_mfma_f32_16x16x32_bf16(ak, aq[kt], a, 0,0,0);
            }
            s[nt] = a;
        }
        __builtin_amdgcn_s_setprio(0);

        if (kb == nkb - 1){          // diagonal tile: causal mask j > q -> NEG_BIG
            int qg = qw + l15;
            #pragma unroll
            for (int nt = 0; nt < 4; ++nt)
                #pragma unroll
                for (int rr = 0; rr < 4; ++rr){
                    int jg = kb*64 + nt*16 + quad*4 + rr;
                    if (jg > qg) s[nt][rr] = NEG_BIG;
                }
        }

        float mx = s[0][0];
        #pragma unroll
        for (int nt = 0; nt < 4; ++nt)
            #pragma unroll
            for (int rr = 0; rr < 4; ++rr) mx = fmaxf(mx, s[nt][rr]);
        mx = fmaxf(mx, __shfl_xor(mx, 16, 64));
        mx = fmaxf(mx, __shfl_xor(mx, 32, 64));

        if (!__all((mx - m_i) <= 8.0f)){
            float mn = fmaxf(m_i, mx);
            float al = exp2f(m_i - mn);
            m_i = mn;
            l_i *= al;
            float al4[4];
            #pragma unroll
            for (int rr = 0; rr < 4; ++rr)
                al4[rr] = __shfl(al, (lane & 48) | (quad*4 + rr), 64);
            #pragma unroll
            for (int vt = 0; vt < 8; ++vt)
                #pragma unroll
                for (int rr = 0; rr < 4; ++rr) oa[vt][rr] *= al4[rr];
        }

        float ps = 0.f;
        #pragma unroll
        for (int nt = 0; nt < 4; ++nt)
            #pragma unroll
            for (int rr = 0; rr < 4; ++rr){
                float p = exp2f(s[nt][rr] - m_i);
                s[nt][rr] = p; ps += p;
            }
        ps += __shfl_xor(ps, 16, 64);
        ps += __shfl_xor(ps, 32, 64);
        l_i += ps;

        u16* pw = Ps[w];
        #pragma unroll
        for (int nt = 0; nt < 4; ++nt){
            uint2 pk;
            asm("v_cvt_pk_bf16_f32 %0, %1, %2" : "=v"(pk.x) : "v"(s[nt][0]), "v"(s[nt][1]));
            asm("v_cvt_pk_bf16_f32 %0, %1, %2" : "=v"(pk.y) : "v"(s[nt][2]), "v"(s[nt][3]));
            int c = (nt*2 + (quad >> 1)) ^ sw;
            *(uint2*)&pw[l15*64 + c*8 + (quad & 1)*4] = pk;
        }

        bf16x8 pa[2];
        #pragma unroll
        for (int kt = 0; kt < 2; ++kt)
            pa[kt] = *(const bf16x8*)&pw[l15*64 + ((kt*4 + quad) ^ sw)*8];

        __builtin_amdgcn_s_setprio(1);
        #pragma unroll
        for (int vt = 0; vt < 8; ++vt){
            #pragma unroll
            for (int kt = 0; kt < 2; ++kt){
                bf16x8 bv = *(const bf16x8*)&vs[(vt*16 + l15)*64 + ((kt*4 + quad) ^ sw)*8];
                oa[vt] = __builtin_amdgcn_mfma_f32_16x16x32_bf16(pa[kt], bv, oa[vt], 0,0,0);
            }
        }
        __builtin_amdgcn_s_setprio(0);

        // end-of-iter: implicit vmcnt(0) drain (prefetch landed under compute) + publish
        __syncthreads();
    }

    #pragma unroll
    for (int rr = 0; rr < 4; ++rr){
        float lv = __shfl(l_i, (lane & 48) | (quad*4 + rr), 64);
        float inv = 1.f / lv;
        int qg = qw + quad*4 + rr;
        #pragma unroll
        for (int vt = 0; vt < 8; ++vt)
            O[qkb + (size_t)qg*128 + vt*16 + l15] = f2bf(oa[vt][rr] * inv);
    }
}

extern "C" void kernel_launch(void* const* d_in, const int* in_sizes, int n_in,
                              void* d_out, int out_size, void* d_ws, size_t ws_size,
                              hipStream_t stream)
{
    const float* x  = (const float*)d_in[0];
    const float* wq = (const float*)d_in[1];
    const float* wk = (const float*)d_in[2];
    const float* wv = (const float*)d_in[3];
    const float* wo = (const float*)d_in[4];
    float* out = (float*)d_out;

    const size_t NT = (size_t)B_ * H_ * S_ * DK_;   // 8388608 elems (16 MiB bf16)
    const size_t NW = (size_t)D_ * D_;              // 4194304 elems (8 MiB bf16)

    if (ws_size >= (size_t)50331648){
        u16* Qw  = (u16*)d_ws;
        u16* Kw  = Qw + NT;
        u16* wvb = Qw + 2*NT;
        u16* wob = wvb + NW;
        u16* xb  = (u16*)d_out;
        u16* wqb = xb + NT;
        u16* wkb = wqb + NW;
        u16* VT  = xb + NT;
        u16* Ow  = Qw;

        cvt_all<<<dim3(12288), 256, 0, stream>>>(x, wq, wk, wv, wo,
                                                 xb, wqb, wkb, wvb, wob);
        gemm256<0,4><<<dim3(8, 16, 2), 512, 0, stream>>>(xb, wqb, wkb, Qw, Kw);
        gemm256<2,2><<<dim3(32, 8, 1), 512, 0, stream>>>(wvb, xb, nullptr, VT, nullptr);
        rope_kernel<<<dim3(4096, 2), 256, 0, stream>>>(Qw, Kw);
        attn_mfma<<<dim3(32, 32), 256, 0, stream>>>(Qw, Kw, VT, Ow);
        gemm256<1,2><<<dim3(16, 16, 1), 512, 0, stream>>>(Ow, wob, nullptr, out, nullptr);
    } else {
        u16* Qw  = (u16*)d_ws;
        u16* Vtd = (u16*)d_out;
        u16* Kw  = (u16*)d_out + NT;
        u16* Ow  = Qw;
        gemm_bt<0><<<dim3(16, 32, 2), 256, 0, stream>>>(x, wq, wk, Qw, Kw);
        gemm_bt<2><<<dim3(32, 16, 1), 256, 0, stream>>>(wv, x, nullptr, Vtd, nullptr);
        rope_kernel<<<dim3(4096, 2), 256, 0, stream>>>(Qw, Kw);
        attn_mfma<<<dim3(32, 32), 256, 0, stream>>>(Qw, Kw, Vtd, Ow);
        gemm_bt<1><<<dim3(16, 32, 1), 256, 0, stream>>>(Ow, wo, nullptr, out, nullptr);
    }
}